// Round 1
// baseline (67.145 us; speedup 1.0000x reference)
//
#include <hip/hip_runtime.h>

// ExponentialUnitNorm: s_t = 0.01*|x_t| + 0.99*s_{t-1};  out_t = x_t / sqrt(s_t)
// x: [B=16, C=2, T=1000, F=481, 2] fp32.  init_state: [1,1,F,1] fp32.
//
// Exact chunked-scan decomposition (affine recurrence):
//   pass1: per (bc, chunk, f) compute zero-init partial sum C_k
//   pass2: per (bc, f) scan chunk transfers: s_{k+1} = a^L * s_k + C_k  (tiny)
//   pass3: per (bc, chunk, f) rerun chunk from its exact init, write out

#define ALPHA_F 0.99f
#define OMA_F   0.01f
#define EPS_F   1e-14f

constexpr int B = 16, C = 2, T = 1000, F = 481;
constexpr int BC = B * C;          // 32
constexpr int NCHUNK = 20;
constexpr int L = T / NCHUNK;      // 50
constexpr int NCHAIN = BC * F;     // 15392

__global__ void k_chunksum(const float* __restrict__ x, float* __restrict__ csum) {
    const int f = threadIdx.x;
    const int chunk = blockIdx.x % NCHUNK;
    const int bc = blockIdx.x / NCHUNK;
    if (f >= F) return;
    const float* xp = x + ((size_t)(bc * T + chunk * L) * F + f) * 2;
    float s = 0.0f;
#pragma unroll 5
    for (int t = 0; t < L; ++t) {
        float2 v = *(const float2*)(xp + (size_t)t * (F * 2));
        float xa = sqrtf(fmaxf(fmaf(v.x, v.x, v.y * v.y), EPS_F));
        s = fmaf(ALPHA_F, s, OMA_F * xa);
    }
    csum[(bc * NCHUNK + chunk) * F + f] = s;
}

__global__ void k_combine(const float* __restrict__ csum,
                          const float* __restrict__ init_state,
                          float* __restrict__ init) {
    const int g = blockIdx.x * blockDim.x + threadIdx.x;
    if (g >= NCHAIN) return;
    const int bc = g / F;
    const int f  = g % F;
    // a^L computed in double once (compile-time foldable loop)
    double aLd = 1.0;
    for (int i = 0; i < L; ++i) aLd *= 0.99;
    const float aL = (float)aLd;
    float s = init_state[f];
    for (int k = 0; k < NCHUNK; ++k) {
        const int idx = (bc * NCHUNK + k) * F + f;
        init[idx] = s;
        s = fmaf(aL, s, csum[idx]);
    }
}

__global__ void k_apply(const float* __restrict__ x,
                        const float* __restrict__ init,
                        float* __restrict__ out) {
    const int f = threadIdx.x;
    const int chunk = blockIdx.x % NCHUNK;
    const int bc = blockIdx.x / NCHUNK;
    if (f >= F) return;
    const size_t base = ((size_t)(bc * T + chunk * L) * F + f) * 2;
    const float* xp = x + base;
    float* op = out + base;
    float s = init[(bc * NCHUNK + chunk) * F + f];
#pragma unroll 5
    for (int t = 0; t < L; ++t) {
        float2 v = *(const float2*)(xp + (size_t)t * (F * 2));
        float xa = sqrtf(fmaxf(fmaf(v.x, v.x, v.y * v.y), EPS_F));
        s = fmaf(ALPHA_F, s, OMA_F * xa);
        const float inv = rsqrtf(s);
        float2 o;
        o.x = v.x * inv;
        o.y = v.y * inv;
        *(float2*)(op + (size_t)t * (F * 2)) = o;
    }
}

extern "C" void kernel_launch(void* const* d_in, const int* in_sizes, int n_in,
                              void* d_out, int out_size, void* d_ws, size_t ws_size,
                              hipStream_t stream) {
    const float* x          = (const float*)d_in[0];
    const float* init_state = (const float*)d_in[1];
    float* out = (float*)d_out;

    float* csum = (float*)d_ws;                    // BC*NCHUNK*F floats = 1.23 MB
    float* init = csum + (size_t)BC * NCHUNK * F;  // same size

    k_chunksum<<<dim3(BC * NCHUNK), 512, 0, stream>>>(x, csum);
    k_combine<<<(NCHAIN + 255) / 256, 256, 0, stream>>>(csum, init_state, init);
    k_apply<<<dim3(BC * NCHUNK), 512, 0, stream>>>(x, init, out);
}